// Round 13
// baseline (1600.918 us; speedup 1.0000x reference)
//
#include <hip/hip_runtime.h>
#include <hip/hip_fp16.h>

#define NN 512
#define NH 256             // half row
#define THREADS 1024       // 16 waves
#define NWAVE 16
#define HROWS 256          // rows per block (half matrix)
#define RPW 16             // rows per wave
#define CPT 16             // exp-phase chunks per thread (HROWS*64/THREADS)
#define NITER 10
// fallback config
#define NBLK 4
#define BROWS 128
#define FTHREADS 512
#define FNWAVE 8
#define FRPW 16

union H2U { uint32_t u; __half2 h; };

__device__ __forceinline__ float wave_reduce_sum(float v) {
    #pragma unroll
    for (int off = 32; off > 0; off >>= 1)
        v += __shfl_xor(v, off, 64);
    return v;   // all 64 lanes hold the sum
}

__device__ __forceinline__ uint4 pack8(const float e[8]) {
    H2U a, b, c, d;
    a.h = __floats2half2_rn(e[0], e[1]);
    b.h = __floats2half2_rn(e[2], e[3]);
    c.h = __floats2half2_rn(e[4], e[5]);
    d.h = __floats2half2_rn(e[6], e[7]);
    return make_uint4(a.u, b.u, c.u, d.u);
}

__device__ __forceinline__ void unpack8(uint4 q, float e[8]) {
    H2U u; float2 f;
    u.u = q.x; f = __half22float2(u.h); e[0] = f.x; e[1] = f.y;
    u.u = q.y; f = __half22float2(u.h); e[2] = f.x; e[3] = f.y;
    u.u = q.z; f = __half22float2(u.h); e[4] = f.x; e[5] = f.y;
    u.u = q.w; f = __half22float2(u.h); e[6] = f.x; e[7] = f.y;
}

// Lane->column map: slot k<4 -> col lane*4+k, slot k>=4 -> col 256+lane*4+
// (k-4). Every global access (fp32 and fp16) is one contiguous 16B per lane.
//
// Persistent cooperative kernel, 256 blocks (R12 lesson: coop launches with
// >256 blocks are rejected by the runtime -> silent no-op with (void);
// every successful coop launch here used <=256). Block = half matrix
// (256 rows, 16 waves). Phases: [exp-stream S->E fp16] -> [10 fused sweeps]
// -> [final out = E*A*B]. Only cross-block data: 2KB partial vector between
// the 2 blocks of a matrix, synced by a per-(iter,matrix) counter using the
// release/acquire pattern that passed correctness in R3-R5 (agent scope =
// device-wide; no XCD-placement assumption). Counters memset to 0 each call.
__global__ __launch_bounds__(THREADS, 1)
void sinkhorn_mega(const float* __restrict__ S,
                   uint32_t* __restrict__ E32,
                   float* __restrict__ out,
                   float* __restrict__ pg,
                   int* __restrict__ cnt,
                   int nmat) {
    const int bid = blockIdx.x;
    const int m = bid % nmat, half = bid / nmat;
    const int tid = threadIdx.x, lane = tid & 63, w = tid >> 6;
    __shared__ float Bsh[NN];
    __shared__ float part[NWAVE][NN];
    __shared__ float Av[HROWS];

    const size_t row0 = (size_t)m * NN + (size_t)half * HROWS;

    // ---- phase E: pure stream exp(S) -> E fp16 for own 256 rows ----
    #pragma unroll 4
    for (int s = 0; s < CPT; ++s) {
        const int chunk = s * THREADS + tid;          // 0..16383
        const size_t row = row0 + (chunk >> 6);
        const int ln = chunk & 63;
        const float* rp = S + row * NN;
        float4 q0 = *reinterpret_cast<const float4*>(rp + ln * 4);
        float4 q1 = *reinterpret_cast<const float4*>(rp + NH + ln * 4);
        float e[8];
        e[0] = __expf(q0.x); e[1] = __expf(q0.y); e[2] = __expf(q0.z); e[3] = __expf(q0.w);
        e[4] = __expf(q1.x); e[5] = __expf(q1.y); e[6] = __expf(q1.z); e[7] = __expf(q1.w);
        *reinterpret_cast<uint4*>(E32 + row * (NN / 2) + ln * 4) = pack8(e);
    }
    __syncthreads();   // own E rows visible block-locally

    // ---- sweeps t=0..9 ----
    float bx[8];
    for (int t = 0; t < NITER; ++t) {
        if (t == 0) {
            #pragma unroll
            for (int k = 0; k < 8; ++k) bx[k] = 1.0f;
        } else {
            const int rb = (t - 1) & 1;
            if (tid < NN) {
                float s = pg[(((size_t)rb * 2 + 0) * nmat + m) * NN + tid]
                        + pg[(((size_t)rb * 2 + 1) * nmat + m) * NN + tid];
                Bsh[tid] = 1.0f / s;    // fixed order -> identical in both blocks
            }
            __syncthreads();
            float4 b0 = *reinterpret_cast<float4*>(&Bsh[lane * 4]);
            float4 b1 = *reinterpret_cast<float4*>(&Bsh[NH + lane * 4]);
            bx[0] = b0.x; bx[1] = b0.y; bx[2] = b0.z; bx[3] = b0.w;
            bx[4] = b1.x; bx[5] = b1.y; bx[6] = b1.z; bx[7] = b1.w;
        }

        float c[8] = {0.f, 0.f, 0.f, 0.f, 0.f, 0.f, 0.f, 0.f};
        #pragma unroll 4
        for (int r = 0; r < RPW; ++r) {
            const int lr = w * RPW + r;
            const size_t row = row0 + lr;
            float e[8];
            unpack8(*reinterpret_cast<const uint4*>(E32 + row * (NN / 2) + lane * 4), e);
            float d = ((e[0]*bx[0] + e[1]*bx[1]) + (e[2]*bx[2] + e[3]*bx[3])) +
                      ((e[4]*bx[4] + e[5]*bx[5]) + (e[6]*bx[6] + e[7]*bx[7]));
            d = wave_reduce_sum(d);
            const float a = 1.0f / d;
            if (lane == 0) Av[lr] = a;
            #pragma unroll
            for (int k = 0; k < 8; ++k) c[k] += e[k] * a;
        }
        *reinterpret_cast<float4*>(&part[w][lane * 4])      = make_float4(c[0], c[1], c[2], c[3]);
        *reinterpret_cast<float4*>(&part[w][NH + lane * 4]) = make_float4(c[4], c[5], c[6], c[7]);
        __syncthreads();
        if (tid < NN) {
            float s2 = 0.f;
            #pragma unroll
            for (int k = 0; k < NWAVE; ++k) s2 += part[k][tid];
            pg[(((size_t)(t & 1) * 2 + half) * nmat + m) * NN + tid] = s2;
        }

        // ---- pair barrier (R3-proven pattern, device scope) ----
        __threadfence();
        __syncthreads();
        int* c_ptr = &cnt[t * nmat + m];
        if (tid == 0)
            __hip_atomic_fetch_add(c_ptr, 1, __ATOMIC_RELEASE, __HIP_MEMORY_SCOPE_AGENT);
        while (__hip_atomic_load(c_ptr, __ATOMIC_ACQUIRE, __HIP_MEMORY_SCOPE_AGENT) < 2)
            __builtin_amdgcn_s_sleep(1);
    }

    // ---- final: B from sweep-9 partials (buf 1); out = E * A * B ----
    {
        const int rb = (NITER - 1) & 1;
        if (tid < NN) {
            float s = pg[(((size_t)rb * 2 + 0) * nmat + m) * NN + tid]
                    + pg[(((size_t)rb * 2 + 1) * nmat + m) * NN + tid];
            Bsh[tid] = 1.0f / s;
        }
        __syncthreads();
        float4 b0 = *reinterpret_cast<float4*>(&Bsh[lane * 4]);
        float4 b1 = *reinterpret_cast<float4*>(&Bsh[NH + lane * 4]);
        bx[0] = b0.x; bx[1] = b0.y; bx[2] = b0.z; bx[3] = b0.w;
        bx[4] = b1.x; bx[5] = b1.y; bx[6] = b1.z; bx[7] = b1.w;

        #pragma unroll 4
        for (int r = 0; r < RPW; ++r) {
            const int lr = w * RPW + r;
            const size_t row = row0 + lr;
            const float a = Av[lr];
            float e[8];
            unpack8(*reinterpret_cast<const uint4*>(E32 + row * (NN / 2) + lane * 4), e);
            *reinterpret_cast<float4*>(out + row * NN + lane * 4) =
                make_float4(e[0]*a*bx[0], e[1]*a*bx[1], e[2]*a*bx[2], e[3]*a*bx[3]);
            *reinterpret_cast<float4*>(out + row * NN + NH + lane * 4) =
                make_float4(e[4]*a*bx[4], e[5]*a*bx[5], e[6]*a*bx[6], e[7]*a*bx[7]);
        }
    }
}

// ---------------- fallback (small ws): R11 multi-kernel, recompute exp ----
__device__ __forceinline__ void load_row8_s(const float* __restrict__ S,
                                            size_t row_g, int lane, float e[8]) {
    float4 q0 = *reinterpret_cast<const float4*>(S + row_g * NN + lane * 4);
    float4 q1 = *reinterpret_cast<const float4*>(S + row_g * NN + NH + lane * 4);
    e[0] = __expf(q0.x); e[1] = __expf(q0.y); e[2] = __expf(q0.z); e[3] = __expf(q0.w);
    e[4] = __expf(q1.x); e[5] = __expf(q1.y); e[6] = __expf(q1.z); e[7] = __expf(q1.w);
}

template<bool FIRST>
__global__ __launch_bounds__(FTHREADS)
void k_sweep_nf(const float* __restrict__ S, const float* __restrict__ pr,
                float* __restrict__ pw, float* __restrict__ A, int nmat) {
    const int m = blockIdx.x % nmat, blk = blockIdx.x / nmat;
    const int lane = threadIdx.x & 63, w = threadIdx.x >> 6;
    __shared__ float Bsh[NN];
    __shared__ float part[FNWAVE][NN];

    if constexpr (!FIRST) {
        float s = 0.f;
        #pragma unroll
        for (int k = 0; k < NBLK; ++k)
            s += pr[((size_t)m * NBLK + k) * NN + threadIdx.x];
        Bsh[threadIdx.x] = 1.0f / s;
        __syncthreads();
    }
    float b[8];
    if constexpr (FIRST) {
        #pragma unroll
        for (int k = 0; k < 8; ++k) b[k] = 1.0f;
    } else {
        float4 b0 = *reinterpret_cast<float4*>(&Bsh[lane * 4]);
        float4 b1 = *reinterpret_cast<float4*>(&Bsh[NH + lane * 4]);
        b[0]=b0.x; b[1]=b0.y; b[2]=b0.z; b[3]=b0.w;
        b[4]=b1.x; b[5]=b1.y; b[6]=b1.z; b[7]=b1.w;
    }
    float c[8] = {0.f,0.f,0.f,0.f,0.f,0.f,0.f,0.f};
    #pragma unroll 4
    for (int r = 0; r < FRPW; ++r) {
        const size_t row_g = (size_t)m * NN + blk * BROWS + w * FRPW + r;
        float e[8];
        load_row8_s(S, row_g, lane, e);
        float d = ((e[0]*b[0]+e[1]*b[1])+(e[2]*b[2]+e[3]*b[3])) +
                  ((e[4]*b[4]+e[5]*b[5])+(e[6]*b[6]+e[7]*b[7]));
        d = wave_reduce_sum(d);
        const float a = 1.0f / d;
        if (lane == 0) A[row_g] = a;
        #pragma unroll
        for (int k = 0; k < 8; ++k) c[k] += e[k] * a;
    }
    *reinterpret_cast<float4*>(&part[w][lane * 4])      = make_float4(c[0],c[1],c[2],c[3]);
    *reinterpret_cast<float4*>(&part[w][NH + lane * 4]) = make_float4(c[4],c[5],c[6],c[7]);
    __syncthreads();
    {
        float s2 = 0.f;
        #pragma unroll
        for (int k = 0; k < FNWAVE; ++k) s2 += part[k][threadIdx.x];
        pw[((size_t)m * NBLK + blk) * NN + threadIdx.x] = s2;
    }
}

__global__ __launch_bounds__(FTHREADS)
void k_final_nf(const float* __restrict__ S, const float* __restrict__ pr,
                const float* __restrict__ A, float* __restrict__ out, int nmat) {
    const int m = blockIdx.x % nmat, blk = blockIdx.x / nmat;
    const int lane = threadIdx.x & 63, w = threadIdx.x >> 6;
    __shared__ float Bsh[NN];
    {
        float s = 0.f;
        #pragma unroll
        for (int k = 0; k < NBLK; ++k)
            s += pr[((size_t)m * NBLK + k) * NN + threadIdx.x];
        Bsh[threadIdx.x] = 1.0f / s;
    }
    __syncthreads();
    float b[8];
    {
        float4 b0 = *reinterpret_cast<float4*>(&Bsh[lane * 4]);
        float4 b1 = *reinterpret_cast<float4*>(&Bsh[NH + lane * 4]);
        b[0]=b0.x; b[1]=b0.y; b[2]=b0.z; b[3]=b0.w;
        b[4]=b1.x; b[5]=b1.y; b[6]=b1.z; b[7]=b1.w;
    }
    #pragma unroll 4
    for (int r = 0; r < FRPW; ++r) {
        const size_t row_g = (size_t)m * NN + blk * BROWS + w * FRPW + r;
        const float a = A[row_g];
        float e[8];
        load_row8_s(S, row_g, lane, e);
        *reinterpret_cast<float4*>(out + row_g * NN + lane * 4) =
            make_float4(e[0]*a*b[0], e[1]*a*b[1], e[2]*a*b[2], e[3]*a*b[3]);
        *reinterpret_cast<float4*>(out + row_g * NN + NH + lane * 4) =
            make_float4(e[4]*a*b[4], e[5]*a*b[5], e[6]*a*b[6], e[7]*a*b[7]);
    }
}

extern "C" void kernel_launch(void* const* d_in, const int* in_sizes, int n_in,
                              void* d_out, int out_size, void* d_ws, size_t ws_size,
                              hipStream_t stream) {
    const float* S = reinterpret_cast<const float*>(d_in[0]);
    float* out = reinterpret_cast<float*>(d_out);
    int nmat = in_sizes[0] / (NN * NN);   // 128 for (8,16,512,512)

    const size_t e_bytes    = (size_t)in_sizes[0] * 2;                 // fp16 E
    const size_t pg_bytes   = 2ull * 2 * nmat * NN * sizeof(float);    // 2 parity x 2 halves
    const size_t cnt_bytes  = (size_t)NITER * nmat * sizeof(int);
    const size_t need       = e_bytes + pg_bytes + cnt_bytes;

    if (d_ws != nullptr && ws_size >= need) {
        uint32_t* E32 = reinterpret_cast<uint32_t*>(d_ws);
        float* pg     = reinterpret_cast<float*>(reinterpret_cast<char*>(d_ws) + e_bytes);
        int*   cnt    = reinterpret_cast<int*>(reinterpret_cast<char*>(d_ws) + e_bytes + pg_bytes);

        (void)hipMemsetAsync(cnt, 0, cnt_bytes, stream);

        dim3 g(2 * nmat), b(THREADS);   // 256 blocks: proven coop size
        void* args[] = { (void*)&S, (void*)&E32, (void*)&out,
                         (void*)&pg, (void*)&cnt, (void*)&nmat };
        (void)hipLaunchCooperativeKernel(reinterpret_cast<const void*>(&sinkhorn_mega),
                                         g, b, args, 0, stream);
    } else {
        // fallback: multi-kernel, recompute exp(S) each sweep
        float* p0 = reinterpret_cast<float*>(d_ws);
        float* p1 = p0 + (size_t)nmat * NBLK * NN;
        float* A  = p1 + (size_t)nmat * NBLK * NN;
        dim3 g(nmat * NBLK), b(FTHREADS);
        k_sweep_nf<true><<<g, b, 0, stream>>>(S, nullptr, p0, A, nmat);
        for (int t = 1; t < NITER; ++t)
            k_sweep_nf<false><<<g, b, 0, stream>>>(S, (t & 1) ? p0 : p1,
                                                   (t & 1) ? p1 : p0, A, nmat);
        k_final_nf<<<g, b, 0, stream>>>(S, p1, A, out, nmat);
    }
}

// Round 14
// 247.066 us; speedup vs baseline: 6.4797x; 6.4797x over previous
//
#include <hip/hip_runtime.h>
#include <hip/hip_fp16.h>

#define NN 512
#define NH 256             // half row
#define NBLK 4             // blocks per matrix (exp0/sweep)
#define BROWS 128          // rows per block (exp0/sweep)
#define THREADS 512        // 8 waves
#define NWAVE 8
#define RPW 16             // rows per wave
#define CPT 16             // exp-phase chunks per thread (BROWS*64/THREADS)
#define NITER 10
// k_final geometry (fill-shaped)
#define FBLK 16            // blocks per matrix
#define FROWS 32           // rows per block
#define FTHR 256           // 4 waves
#define FSTEP 8            // FROWS*64/FTHR

union H2U { uint32_t u; __half2 h; };

__device__ __forceinline__ float wave_reduce_sum(float v) {
    #pragma unroll
    for (int off = 32; off > 0; off >>= 1)
        v += __shfl_xor(v, off, 64);
    return v;   // all 64 lanes hold the sum
}

__device__ __forceinline__ uint4 pack8(const float e[8]) {
    H2U a, b, c, d;
    a.h = __floats2half2_rn(e[0], e[1]);
    b.h = __floats2half2_rn(e[2], e[3]);
    c.h = __floats2half2_rn(e[4], e[5]);
    d.h = __floats2half2_rn(e[6], e[7]);
    return make_uint4(a.u, b.u, c.u, d.u);
}

__device__ __forceinline__ void unpack8(uint4 q, float e[8]) {
    H2U u; float2 f;
    u.u = q.x; f = __half22float2(u.h); e[0] = f.x; e[1] = f.y;
    u.u = q.y; f = __half22float2(u.h); e[2] = f.x; e[3] = f.y;
    u.u = q.z; f = __half22float2(u.h); e[4] = f.x; e[5] = f.y;
    u.u = q.w; f = __half22float2(u.h); e[6] = f.x; e[7] = f.y;
}

// Lane->column map: slot k<4 -> col lane*4+k, slot k>=4 -> col 256+lane*4+
// (k-4). Every global access (fp32/fp16) is one contiguous 16B per lane.
//
// Structure (R13 lesson: ALL intra-kernel cross-block sync is poison --
// all-thread agent-scope spins serialized the memory system, 1600us; the
// kernel-boundary pipeline at 253us is the right skeleton):
//   k_exp0  : [stream exp(S)->E fp16 for own 128 rows] -> __syncthreads ->
//             [sweep0 with B=1: A0 + col partials] (phase order proven in R13)
//   k_sweep : x9, unchanged from R11 (measured ~11us each)
//   k_final : fill-shaped streamer (2048 x 256thr), tiny B head, pure
//             read-E / write-out (R11 inference: old k_final ~45-60us at
//             3.2 TB/s was the fattest remaining target)

__global__ __launch_bounds__(THREADS)
void k_exp0(const float* __restrict__ S, uint32_t* __restrict__ E32,
            float* __restrict__ A, float* __restrict__ pw, int nmat) {
    const int m = blockIdx.x % nmat, blk = blockIdx.x / nmat;
    const int tid = threadIdx.x, lane = tid & 63, w = tid >> 6;
    __shared__ float part[NWAVE][NN];

    const size_t row0 = (size_t)m * NN + (size_t)blk * BROWS;

    // ---- phase 1: pure stream exp(S) -> E fp16 for own 128 rows ----
    #pragma unroll 4
    for (int s = 0; s < CPT; ++s) {
        const int chunk = s * THREADS + tid;
        const size_t row = row0 + (chunk >> 6);
        const int ln = chunk & 63;
        const float* rp = S + row * NN;
        float4 q0 = *reinterpret_cast<const float4*>(rp + ln * 4);
        float4 q1 = *reinterpret_cast<const float4*>(rp + NH + ln * 4);
        float e[8];
        e[0] = __expf(q0.x); e[1] = __expf(q0.y); e[2] = __expf(q0.z); e[3] = __expf(q0.w);
        e[4] = __expf(q1.x); e[5] = __expf(q1.y); e[6] = __expf(q1.z); e[7] = __expf(q1.w);
        *reinterpret_cast<uint4*>(E32 + row * (NN / 2) + ln * 4) = pack8(e);
    }
    __syncthreads();   // block-local E writes visible (R13-proven sequence)

    // ---- phase 2: sweep0 (B = 1) reading own E back (L2/L3-hot) ----
    float c[8] = {0.f, 0.f, 0.f, 0.f, 0.f, 0.f, 0.f, 0.f};
    #pragma unroll 4
    for (int r = 0; r < RPW; ++r) {
        const size_t row = row0 + w * RPW + r;
        float e[8];
        unpack8(*reinterpret_cast<const uint4*>(E32 + row * (NN / 2) + lane * 4), e);
        float d = ((e[0]+e[1]) + (e[2]+e[3])) + ((e[4]+e[5]) + (e[6]+e[7]));
        d = wave_reduce_sum(d);
        const float a = 1.0f / d;
        if (lane == 0) A[row] = a;
        #pragma unroll
        for (int k = 0; k < 8; ++k) c[k] += e[k] * a;
    }
    *reinterpret_cast<float4*>(&part[w][lane * 4])      = make_float4(c[0], c[1], c[2], c[3]);
    *reinterpret_cast<float4*>(&part[w][NH + lane * 4]) = make_float4(c[4], c[5], c[6], c[7]);
    __syncthreads();
    {
        float s2 = 0.f;
        #pragma unroll
        for (int k = 0; k < NWAVE; ++k) s2 += part[k][tid];
        pw[((size_t)m * NBLK + blk) * NN + tid] = s2;
    }
}

__global__ __launch_bounds__(THREADS)
void k_sweep(const uint32_t* __restrict__ E32,
             const float* __restrict__ pr, float* __restrict__ pw,
             float* __restrict__ A, int nmat) {
    const int m = blockIdx.x % nmat, blk = blockIdx.x / nmat;
    const int tid = threadIdx.x, lane = tid & 63, w = tid >> 6;
    __shared__ float Bsh[NN];
    __shared__ float part[NWAVE][NN];

    {   // B head: complete previous col sums (fixed order, deterministic)
        float s = 0.f;
        #pragma unroll
        for (int k = 0; k < NBLK; ++k) s += pr[((size_t)m * NBLK + k) * NN + tid];
        Bsh[tid] = 1.0f / s;
    }
    __syncthreads();

    float b[8];
    {
        float4 b0 = *reinterpret_cast<float4*>(&Bsh[lane * 4]);
        float4 b1 = *reinterpret_cast<float4*>(&Bsh[NH + lane * 4]);
        b[0]=b0.x; b[1]=b0.y; b[2]=b0.z; b[3]=b0.w;
        b[4]=b1.x; b[5]=b1.y; b[6]=b1.z; b[7]=b1.w;
    }
    float c[8] = {0.f,0.f,0.f,0.f,0.f,0.f,0.f,0.f};

    #pragma unroll 4
    for (int r = 0; r < RPW; ++r) {
        const size_t row = (size_t)m * NN + blk * BROWS + w * RPW + r;
        float e[8];
        unpack8(*reinterpret_cast<const uint4*>(E32 + row * (NN / 2) + lane * 4), e);
        float d = ((e[0]*b[0]+e[1]*b[1]) + (e[2]*b[2]+e[3]*b[3])) +
                  ((e[4]*b[4]+e[5]*b[5]) + (e[6]*b[6]+e[7]*b[7]));
        d = wave_reduce_sum(d);
        const float a = 1.0f / d;
        if (lane == 0) A[row] = a;
        #pragma unroll
        for (int k = 0; k < 8; ++k) c[k] += e[k] * a;
    }
    *reinterpret_cast<float4*>(&part[w][lane * 4])      = make_float4(c[0],c[1],c[2],c[3]);
    *reinterpret_cast<float4*>(&part[w][NH + lane * 4]) = make_float4(c[4],c[5],c[6],c[7]);
    __syncthreads();
    {
        float s2 = 0.f;
        #pragma unroll
        for (int k = 0; k < NWAVE; ++k) s2 += part[k][tid];
        pw[((size_t)m * NBLK + blk) * NN + tid] = s2;
    }
}

__global__ __launch_bounds__(FTHR)
void k_final(const uint32_t* __restrict__ E32,
             const float* __restrict__ pr, const float* __restrict__ A,
             float* __restrict__ out, int nmat) {
    const int m = blockIdx.x >> 4, blk = blockIdx.x & 15;
    const int tid = threadIdx.x, lane = tid & 63;
    __shared__ float Bsh[NN];

    {   // B head: 2 columns per thread
        #pragma unroll
        for (int h = 0; h < 2; ++h) {
            const int j = h * FTHR + tid;
            float s = 0.f;
            #pragma unroll
            for (int k = 0; k < NBLK; ++k) s += pr[((size_t)m * NBLK + k) * NN + j];
            Bsh[j] = 1.0f / s;
        }
    }
    __syncthreads();

    float b[8];
    {
        float4 b0 = *reinterpret_cast<float4*>(&Bsh[lane * 4]);
        float4 b1 = *reinterpret_cast<float4*>(&Bsh[NH + lane * 4]);
        b[0]=b0.x; b[1]=b0.y; b[2]=b0.z; b[3]=b0.w;
        b[4]=b1.x; b[5]=b1.y; b[6]=b1.z; b[7]=b1.w;
    }

    const size_t row0 = (size_t)m * NN + (size_t)blk * FROWS;
    #pragma unroll 4
    for (int s = 0; s < FSTEP; ++s) {
        const int chunk = s * FTHR + tid;          // wave-uniform row per step
        const size_t row = row0 + (chunk >> 6);
        const int ln = chunk & 63;
        const float a = A[row];                    // wave-uniform broadcast
        float e[8];
        unpack8(*reinterpret_cast<const uint4*>(E32 + row * (NN / 2) + ln * 4), e);
        float* op = out + row * NN;
        *reinterpret_cast<float4*>(op + ln * 4) =
            make_float4(e[0]*a*b[0], e[1]*a*b[1], e[2]*a*b[2], e[3]*a*b[3]);
        *reinterpret_cast<float4*>(op + NH + ln * 4) =
            make_float4(e[4]*a*b[4], e[5]*a*b[5], e[6]*a*b[6], e[7]*a*b[7]);
    }
}

// ---------------- fallback (small ws): recompute exp, multi-kernel ----
__device__ __forceinline__ void load_row8_s(const float* __restrict__ S,
                                            size_t row_g, int lane, float e[8]) {
    float4 q0 = *reinterpret_cast<const float4*>(S + row_g * NN + lane * 4);
    float4 q1 = *reinterpret_cast<const float4*>(S + row_g * NN + NH + lane * 4);
    e[0] = __expf(q0.x); e[1] = __expf(q0.y); e[2] = __expf(q0.z); e[3] = __expf(q0.w);
    e[4] = __expf(q1.x); e[5] = __expf(q1.y); e[6] = __expf(q1.z); e[7] = __expf(q1.w);
}

template<bool FIRST>
__global__ __launch_bounds__(THREADS)
void k_sweep_nf(const float* __restrict__ S, const float* __restrict__ pr,
                float* __restrict__ pw, float* __restrict__ A, int nmat) {
    const int m = blockIdx.x % nmat, blk = blockIdx.x / nmat;
    const int tid = threadIdx.x, lane = tid & 63, w = tid >> 6;
    __shared__ float Bsh[NN];
    __shared__ float part[NWAVE][NN];

    if constexpr (!FIRST) {
        float s = 0.f;
        #pragma unroll
        for (int k = 0; k < NBLK; ++k) s += pr[((size_t)m * NBLK + k) * NN + tid];
        Bsh[tid] = 1.0f / s;
        __syncthreads();
    }
    float b[8];
    if constexpr (FIRST) {
        #pragma unroll
        for (int k = 0; k < 8; ++k) b[k] = 1.0f;
    } else {
        float4 b0 = *reinterpret_cast<float4*>(&Bsh[lane * 4]);
        float4 b1 = *reinterpret_cast<float4*>(&Bsh[NH + lane * 4]);
        b[0]=b0.x; b[1]=b0.y; b[2]=b0.z; b[3]=b0.w;
        b[4]=b1.x; b[5]=b1.y; b[6]=b1.z; b[7]=b1.w;
    }
    float c[8] = {0.f,0.f,0.f,0.f,0.f,0.f,0.f,0.f};
    #pragma unroll 4
    for (int r = 0; r < RPW; ++r) {
        const size_t row_g = (size_t)m * NN + blk * BROWS + w * RPW + r;
        float e[8];
        load_row8_s(S, row_g, lane, e);
        float d = ((e[0]*b[0]+e[1]*b[1])+(e[2]*b[2]+e[3]*b[3])) +
                  ((e[4]*b[4]+e[5]*b[5])+(e[6]*b[6]+e[7]*b[7]));
        d = wave_reduce_sum(d);
        const float a = 1.0f / d;
        if (lane == 0) A[row_g] = a;
        #pragma unroll
        for (int k = 0; k < 8; ++k) c[k] += e[k] * a;
    }
    *reinterpret_cast<float4*>(&part[w][lane * 4])      = make_float4(c[0],c[1],c[2],c[3]);
    *reinterpret_cast<float4*>(&part[w][NH + lane * 4]) = make_float4(c[4],c[5],c[6],c[7]);
    __syncthreads();
    {
        float s2 = 0.f;
        #pragma unroll
        for (int k = 0; k < NWAVE; ++k) s2 += part[k][tid];
        pw[((size_t)m * NBLK + blk) * NN + tid] = s2;
    }
}

__global__ __launch_bounds__(THREADS)
void k_final_nf(const float* __restrict__ S, const float* __restrict__ pr,
                const float* __restrict__ A, float* __restrict__ out, int nmat) {
    const int m = blockIdx.x % nmat, blk = blockIdx.x / nmat;
    const int tid = threadIdx.x, lane = tid & 63, w = tid >> 6;
    __shared__ float Bsh[NN];
    {
        float s = 0.f;
        #pragma unroll
        for (int k = 0; k < NBLK; ++k) s += pr[((size_t)m * NBLK + k) * NN + tid];
        Bsh[tid] = 1.0f / s;
    }
    __syncthreads();
    float b[8];
    {
        float4 b0 = *reinterpret_cast<float4*>(&Bsh[lane * 4]);
        float4 b1 = *reinterpret_cast<float4*>(&Bsh[NH + lane * 4]);
        b[0]=b0.x; b[1]=b0.y; b[2]=b0.z; b[3]=b0.w;
        b[4]=b1.x; b[5]=b1.y; b[6]=b1.z; b[7]=b1.w;
    }
    #pragma unroll 4
    for (int r = 0; r < RPW; ++r) {
        const size_t row_g = (size_t)m * NN + blk * BROWS + w * RPW + r;
        const float a = A[row_g];
        float e[8];
        load_row8_s(S, row_g, lane, e);
        *reinterpret_cast<float4*>(out + row_g * NN + lane * 4) =
            make_float4(e[0]*a*b[0], e[1]*a*b[1], e[2]*a*b[2], e[3]*a*b[3]);
        *reinterpret_cast<float4*>(out + row_g * NN + NH + lane * 4) =
            make_float4(e[4]*a*b[4], e[5]*a*b[5], e[6]*a*b[6], e[7]*a*b[7]);
    }
}

extern "C" void kernel_launch(void* const* d_in, const int* in_sizes, int n_in,
                              void* d_out, int out_size, void* d_ws, size_t ws_size,
                              hipStream_t stream) {
    const float* S = reinterpret_cast<const float*>(d_in[0]);
    float* out = reinterpret_cast<float*>(d_out);
    const int nmat = in_sizes[0] / (NN * NN);   // 128 for (8,16,512,512)

    const size_t e_bytes   = (size_t)in_sizes[0] * 2;            // fp16 E
    const size_t pa_floats = (size_t)nmat * NBLK * NN;           // one partial buffer
    const size_t need      = e_bytes + (2 * pa_floats + (size_t)nmat * NN) * 4;

    if (d_ws != nullptr && ws_size >= need) {
        uint32_t* E32 = reinterpret_cast<uint32_t*>(d_ws);
        float* p0 = reinterpret_cast<float*>(reinterpret_cast<char*>(d_ws) + e_bytes);
        float* p1 = p0 + pa_floats;
        float* A  = p1 + pa_floats;

        dim3 g(nmat * NBLK), b(THREADS);
        k_exp0<<<g, b, 0, stream>>>(S, E32, A, p0, nmat);         // sweep 0, writes p0
        for (int t = 1; t < NITER; ++t)
            k_sweep<<<g, b, 0, stream>>>(E32, (t & 1) ? p0 : p1,
                                         (t & 1) ? p1 : p0, A, nmat);
        k_final<<<dim3(nmat * FBLK), dim3(FTHR), 0, stream>>>(E32, p1, A, out, nmat);
    } else {
        float* p0 = reinterpret_cast<float*>(d_ws);
        float* p1 = p0 + pa_floats;
        float* A  = p1 + pa_floats;
        dim3 g(nmat * NBLK), b(THREADS);
        k_sweep_nf<true><<<g, b, 0, stream>>>(S, nullptr, p0, A, nmat);
        for (int t = 1; t < NITER; ++t)
            k_sweep_nf<false><<<g, b, 0, stream>>>(S, (t & 1) ? p0 : p1,
                                                   (t & 1) ? p1 : p0, A, nmat);
        k_final_nf<<<g, b, 0, stream>>>(S, p1, A, out, nmat);
    }
}

// Round 15
// 245.762 us; speedup vs baseline: 6.5141x; 1.0053x over previous
//
#include <hip/hip_runtime.h>
#include <hip/hip_fp16.h>

#define NN 512
#define NH 256             // half row
#define NBLK 4             // blocks per matrix (sweeps)
#define BROWS 128          // rows per block (sweeps)
#define THREADS 512        // 8 waves (sweeps)
#define NWAVE 8
#define RPW 16             // rows per wave (sweeps)
#define NITER 10
// k_exp0 geometry (full-occupancy: 2048 blocks x 256 thr, 32 rows/block)
#define XBLK 16            // blocks per matrix
#define XROWS 32           // rows per block
#define XTHR 256           // 4 waves
#define XWAVE 4
#define XRPW 8             // rows per wave (sweep0 phase)
#define XCPT 8             // exp chunks per thread (XROWS*64/XTHR)
// k_final geometry
#define FBLK 16
#define FROWS 32
#define FTHR 256
#define FSTEP 8

union H2U { uint32_t u; __half2 h; };

__device__ __forceinline__ float wave_reduce_sum(float v) {
    #pragma unroll
    for (int off = 32; off > 0; off >>= 1)
        v += __shfl_xor(v, off, 64);
    return v;   // all 64 lanes hold the sum
}

__device__ __forceinline__ uint4 pack8(const float e[8]) {
    H2U a, b, c, d;
    a.h = __floats2half2_rn(e[0], e[1]);
    b.h = __floats2half2_rn(e[2], e[3]);
    c.h = __floats2half2_rn(e[4], e[5]);
    d.h = __floats2half2_rn(e[6], e[7]);
    return make_uint4(a.u, b.u, c.u, d.u);
}

__device__ __forceinline__ void unpack8(uint4 q, float e[8]) {
    H2U u; float2 f;
    u.u = q.x; f = __half22float2(u.h); e[0] = f.x; e[1] = f.y;
    u.u = q.y; f = __half22float2(u.h); e[2] = f.x; e[3] = f.y;
    u.u = q.z; f = __half22float2(u.h); e[4] = f.x; e[5] = f.y;
    u.u = q.w; f = __half22float2(u.h); e[6] = f.x; e[7] = f.y;
}

// Lane->column map: slot k<4 -> col lane*4+k, slot k>=4 -> col 256+lane*4+
// (k-4). Every global access (fp32/fp16) is one contiguous 16B per lane.
//
// R14 lesson: HBM-latency-exposed streams need FULL occupancy -- <=512-block
// kernels plateau at 1.4-2.2 TB/s while 2048-block streams hit 4-7 TB/s.
// k_exp0: 2048 x 256thr (8 blocks/CU), block = 32 rows; [stream exp(S)->E]
// -> syncthreads -> [sweep0, B=1] writing 16 partials/matrix (p16).
// k_sweep<NPART>: unchanged 512x512 geometry (E reads are L2/L3-served, 50%
// occupancy suffices); t=1 reads the 16-wide p16, t>=2 read 4-wide.
// k_final: fill-shaped 2048 x 256.

__global__ __launch_bounds__(XTHR)
void k_exp0(const float* __restrict__ S, uint32_t* __restrict__ E32,
            float* __restrict__ A, float* __restrict__ p16, int nmat) {
    const int m = blockIdx.x % nmat, blk = blockIdx.x / nmat;
    const int tid = threadIdx.x, lane = tid & 63, w = tid >> 6;
    __shared__ float part[XWAVE][NN];

    const size_t row0 = (size_t)m * NN + (size_t)blk * XROWS;

    // ---- phase 1: stream exp(S) -> E fp16 for own 32 rows ----
    #pragma unroll 4
    for (int s = 0; s < XCPT; ++s) {
        const int chunk = s * XTHR + tid;      // 0..2047
        const size_t row = row0 + (chunk >> 6);
        const int ln = chunk & 63;
        const float* rp = S + row * NN;
        float4 q0 = *reinterpret_cast<const float4*>(rp + ln * 4);
        float4 q1 = *reinterpret_cast<const float4*>(rp + NH + ln * 4);
        float e[8];
        e[0] = __expf(q0.x); e[1] = __expf(q0.y); e[2] = __expf(q0.z); e[3] = __expf(q0.w);
        e[4] = __expf(q1.x); e[5] = __expf(q1.y); e[6] = __expf(q1.z); e[7] = __expf(q1.w);
        *reinterpret_cast<uint4*>(E32 + row * (NN / 2) + ln * 4) = pack8(e);
    }
    __syncthreads();   // own E rows visible block-locally

    // ---- phase 2: sweep0 (B = 1) reading own E back (L2-hot) ----
    float c[8] = {0.f, 0.f, 0.f, 0.f, 0.f, 0.f, 0.f, 0.f};
    #pragma unroll 4
    for (int r = 0; r < XRPW; ++r) {
        const size_t row = row0 + w * XRPW + r;
        float e[8];
        unpack8(*reinterpret_cast<const uint4*>(E32 + row * (NN / 2) + lane * 4), e);
        float d = ((e[0]+e[1]) + (e[2]+e[3])) + ((e[4]+e[5]) + (e[6]+e[7]));
        d = wave_reduce_sum(d);
        const float a = 1.0f / d;
        if (lane == 0) A[row] = a;
        #pragma unroll
        for (int k = 0; k < 8; ++k) c[k] += e[k] * a;
    }
    *reinterpret_cast<float4*>(&part[w][lane * 4])      = make_float4(c[0], c[1], c[2], c[3]);
    *reinterpret_cast<float4*>(&part[w][NH + lane * 4]) = make_float4(c[4], c[5], c[6], c[7]);
    __syncthreads();
    #pragma unroll
    for (int h = 0; h < 2; ++h) {
        const int j = h * XTHR + tid;
        float s2 = (part[0][j] + part[1][j]) + (part[2][j] + part[3][j]);
        p16[((size_t)m * XBLK + blk) * NN + j] = s2;
    }
}

template<int NPART>
__global__ __launch_bounds__(THREADS)
void k_sweep(const uint32_t* __restrict__ E32,
             const float* __restrict__ pr, float* __restrict__ pw,
             float* __restrict__ A, int nmat) {
    const int m = blockIdx.x % nmat, blk = blockIdx.x / nmat;
    const int tid = threadIdx.x, lane = tid & 63, w = tid >> 6;
    __shared__ float Bsh[NN];
    __shared__ float part[NWAVE][NN];

    {   // B head: complete previous col sums (fixed order, deterministic)
        float s = 0.f;
        #pragma unroll
        for (int k = 0; k < NPART; ++k) s += pr[((size_t)m * NPART + k) * NN + tid];
        Bsh[tid] = 1.0f / s;
    }
    __syncthreads();

    float b[8];
    {
        float4 b0 = *reinterpret_cast<float4*>(&Bsh[lane * 4]);
        float4 b1 = *reinterpret_cast<float4*>(&Bsh[NH + lane * 4]);
        b[0]=b0.x; b[1]=b0.y; b[2]=b0.z; b[3]=b0.w;
        b[4]=b1.x; b[5]=b1.y; b[6]=b1.z; b[7]=b1.w;
    }
    float c[8] = {0.f,0.f,0.f,0.f,0.f,0.f,0.f,0.f};

    #pragma unroll 4
    for (int r = 0; r < RPW; ++r) {
        const size_t row = (size_t)m * NN + blk * BROWS + w * RPW + r;
        float e[8];
        unpack8(*reinterpret_cast<const uint4*>(E32 + row * (NN / 2) + lane * 4), e);
        float d = ((e[0]*b[0]+e[1]*b[1]) + (e[2]*b[2]+e[3]*b[3])) +
                  ((e[4]*b[4]+e[5]*b[5]) + (e[6]*b[6]+e[7]*b[7]));
        d = wave_reduce_sum(d);
        const float a = 1.0f / d;
        if (lane == 0) A[row] = a;
        #pragma unroll
        for (int k = 0; k < 8; ++k) c[k] += e[k] * a;
    }
    *reinterpret_cast<float4*>(&part[w][lane * 4])      = make_float4(c[0],c[1],c[2],c[3]);
    *reinterpret_cast<float4*>(&part[w][NH + lane * 4]) = make_float4(c[4],c[5],c[6],c[7]);
    __syncthreads();
    {
        float s2 = 0.f;
        #pragma unroll
        for (int k = 0; k < NWAVE; ++k) s2 += part[k][tid];
        pw[((size_t)m * NBLK + blk) * NN + tid] = s2;
    }
}

__global__ __launch_bounds__(FTHR)
void k_final(const uint32_t* __restrict__ E32,
             const float* __restrict__ pr, const float* __restrict__ A,
             float* __restrict__ out, int nmat) {
    const int m = blockIdx.x >> 4, blk = blockIdx.x & 15;
    const int tid = threadIdx.x, lane = tid & 63;
    __shared__ float Bsh[NN];

    {   // B head: 2 columns per thread
        #pragma unroll
        for (int h = 0; h < 2; ++h) {
            const int j = h * FTHR + tid;
            float s = 0.f;
            #pragma unroll
            for (int k = 0; k < NBLK; ++k) s += pr[((size_t)m * NBLK + k) * NN + j];
            Bsh[j] = 1.0f / s;
        }
    }
    __syncthreads();

    float b[8];
    {
        float4 b0 = *reinterpret_cast<float4*>(&Bsh[lane * 4]);
        float4 b1 = *reinterpret_cast<float4*>(&Bsh[NH + lane * 4]);
        b[0]=b0.x; b[1]=b0.y; b[2]=b0.z; b[3]=b0.w;
        b[4]=b1.x; b[5]=b1.y; b[6]=b1.z; b[7]=b1.w;
    }

    const size_t row0 = (size_t)m * NN + (size_t)blk * FROWS;
    #pragma unroll 4
    for (int s = 0; s < FSTEP; ++s) {
        const int chunk = s * FTHR + tid;          // wave-uniform row per step
        const size_t row = row0 + (chunk >> 6);
        const int ln = chunk & 63;
        const float a = A[row];                    // wave-uniform broadcast
        float e[8];
        unpack8(*reinterpret_cast<const uint4*>(E32 + row * (NN / 2) + ln * 4), e);
        float* op = out + row * NN;
        *reinterpret_cast<float4*>(op + ln * 4) =
            make_float4(e[0]*a*b[0], e[1]*a*b[1], e[2]*a*b[2], e[3]*a*b[3]);
        *reinterpret_cast<float4*>(op + NH + ln * 4) =
            make_float4(e[4]*a*b[4], e[5]*a*b[5], e[6]*a*b[6], e[7]*a*b[7]);
    }
}

// ---------------- fallback (small ws): recompute exp, multi-kernel ----
__device__ __forceinline__ void load_row8_s(const float* __restrict__ S,
                                            size_t row_g, int lane, float e[8]) {
    float4 q0 = *reinterpret_cast<const float4*>(S + row_g * NN + lane * 4);
    float4 q1 = *reinterpret_cast<const float4*>(S + row_g * NN + NH + lane * 4);
    e[0] = __expf(q0.x); e[1] = __expf(q0.y); e[2] = __expf(q0.z); e[3] = __expf(q0.w);
    e[4] = __expf(q1.x); e[5] = __expf(q1.y); e[6] = __expf(q1.z); e[7] = __expf(q1.w);
}

template<bool FIRST>
__global__ __launch_bounds__(THREADS)
void k_sweep_nf(const float* __restrict__ S, const float* __restrict__ pr,
                float* __restrict__ pw, float* __restrict__ A, int nmat) {
    const int m = blockIdx.x % nmat, blk = blockIdx.x / nmat;
    const int tid = threadIdx.x, lane = tid & 63, w = tid >> 6;
    __shared__ float Bsh[NN];
    __shared__ float part[NWAVE][NN];

    if constexpr (!FIRST) {
        float s = 0.f;
        #pragma unroll
        for (int k = 0; k < NBLK; ++k) s += pr[((size_t)m * NBLK + k) * NN + tid];
        Bsh[tid] = 1.0f / s;
        __syncthreads();
    }
    float b[8];
    if constexpr (FIRST) {
        #pragma unroll
        for (int k = 0; k < 8; ++k) b[k] = 1.0f;
    } else {
        float4 b0 = *reinterpret_cast<float4*>(&Bsh[lane * 4]);
        float4 b1 = *reinterpret_cast<float4*>(&Bsh[NH + lane * 4]);
        b[0]=b0.x; b[1]=b0.y; b[2]=b0.z; b[3]=b0.w;
        b[4]=b1.x; b[5]=b1.y; b[6]=b1.z; b[7]=b1.w;
    }
    float c[8] = {0.f,0.f,0.f,0.f,0.f,0.f,0.f,0.f};
    #pragma unroll 4
    for (int r = 0; r < RPW; ++r) {
        const size_t row_g = (size_t)m * NN + blk * BROWS + w * RPW + r;
        float e[8];
        load_row8_s(S, row_g, lane, e);
        float d = ((e[0]*b[0]+e[1]*b[1])+(e[2]*b[2]+e[3]*b[3])) +
                  ((e[4]*b[4]+e[5]*b[5])+(e[6]*b[6]+e[7]*b[7]));
        d = wave_reduce_sum(d);
        const float a = 1.0f / d;
        if (lane == 0) A[row_g] = a;
        #pragma unroll
        for (int k = 0; k < 8; ++k) c[k] += e[k] * a;
    }
    *reinterpret_cast<float4*>(&part[w][lane * 4])      = make_float4(c[0],c[1],c[2],c[3]);
    *reinterpret_cast<float4*>(&part[w][NH + lane * 4]) = make_float4(c[4],c[5],c[6],c[7]);
    __syncthreads();
    {
        float s2 = 0.f;
        #pragma unroll
        for (int k = 0; k < NWAVE; ++k) s2 += part[k][tid];
        pw[((size_t)m * NBLK + blk) * NN + tid] = s2;
    }
}

__global__ __launch_bounds__(THREADS)
void k_final_nf(const float* __restrict__ S, const float* __restrict__ pr,
                const float* __restrict__ A, float* __restrict__ out, int nmat) {
    const int m = blockIdx.x % nmat, blk = blockIdx.x / nmat;
    const int tid = threadIdx.x, lane = tid & 63, w = tid >> 6;
    __shared__ float Bsh[NN];
    {
        float s = 0.f;
        #pragma unroll
        for (int k = 0; k < NBLK; ++k) s += pr[((size_t)m * NBLK + k) * NN + tid];
        Bsh[tid] = 1.0f / s;
    }
    __syncthreads();
    float b[8];
    {
        float4 b0 = *reinterpret_cast<float4*>(&Bsh[lane * 4]);
        float4 b1 = *reinterpret_cast<float4*>(&Bsh[NH + lane * 4]);
        b[0]=b0.x; b[1]=b0.y; b[2]=b0.z; b[3]=b0.w;
        b[4]=b1.x; b[5]=b1.y; b[6]=b1.z; b[7]=b1.w;
    }
    #pragma unroll 4
    for (int r = 0; r < RPW; ++r) {
        const size_t row_g = (size_t)m * NN + blk * BROWS + w * RPW + r;
        const float a = A[row_g];
        float e[8];
        load_row8_s(S, row_g, lane, e);
        *reinterpret_cast<float4*>(out + row_g * NN + lane * 4) =
            make_float4(e[0]*a*b[0], e[1]*a*b[1], e[2]*a*b[2], e[3]*a*b[3]);
        *reinterpret_cast<float4*>(out + row_g * NN + NH + lane * 4) =
            make_float4(e[4]*a*b[4], e[5]*a*b[5], e[6]*a*b[6], e[7]*a*b[7]);
    }
}

extern "C" void kernel_launch(void* const* d_in, const int* in_sizes, int n_in,
                              void* d_out, int out_size, void* d_ws, size_t ws_size,
                              hipStream_t stream) {
    const float* S = reinterpret_cast<const float*>(d_in[0]);
    float* out = reinterpret_cast<float*>(d_out);
    const int nmat = in_sizes[0] / (NN * NN);   // 128 for (8,16,512,512)

    const size_t e_bytes    = (size_t)in_sizes[0] * 2;            // fp16 E
    const size_t p16_floats = (size_t)nmat * XBLK * NN;           // sweep0 partials
    const size_t pa_floats  = (size_t)nmat * NBLK * NN;           // sweep partials
    const size_t a_floats   = (size_t)nmat * NN;
    const size_t need = e_bytes + (p16_floats + 2 * pa_floats + a_floats) * 4;

    if (d_ws != nullptr && ws_size >= need) {
        uint32_t* E32 = reinterpret_cast<uint32_t*>(d_ws);
        float* p16 = reinterpret_cast<float*>(reinterpret_cast<char*>(d_ws) + e_bytes);
        float* p0  = p16 + p16_floats;
        float* p1  = p0 + pa_floats;
        float* A   = p1 + pa_floats;
        float* bufs[2] = { p0, p1 };

        dim3 gs(nmat * NBLK), bs(THREADS);
        k_exp0<<<dim3(nmat * XBLK), dim3(XTHR), 0, stream>>>(S, E32, A, p16, nmat);
        k_sweep<XBLK><<<gs, bs, 0, stream>>>(E32, p16, p0, A, nmat);         // t=1
        for (int t = 2; t < NITER; ++t)                                      // t=2..9
            k_sweep<NBLK><<<gs, bs, 0, stream>>>(E32, bufs[t & 1],
                                                 bufs[1 - (t & 1)], A, nmat);
        // t=9 wrote bufs[1-(9&1)] = bufs[0] = p0
        k_final<<<dim3(nmat * FBLK), dim3(FTHR), 0, stream>>>(E32, p0, A, out, nmat);
    } else {
        float* p0 = reinterpret_cast<float*>(d_ws);
        float* p1 = p0 + pa_floats;
        float* A  = p1 + pa_floats;
        dim3 g(nmat * NBLK), b(THREADS);
        k_sweep_nf<true><<<g, b, 0, stream>>>(S, nullptr, p0, A, nmat);
        for (int t = 1; t < NITER; ++t)
            k_sweep_nf<false><<<g, b, 0, stream>>>(S, (t & 1) ? p0 : p1,
                                                   (t & 1) ? p1 : p0, A, nmat);
        k_final_nf<<<g, b, 0, stream>>>(S, p1, A, out, nmat);
    }
}